// Round 1
// baseline (480.034 us; speedup 1.0000x reference)
//
#include <hip/hip_runtime.h>
#include <hip/hip_bf16.h>
#include <cstdint>
#include <cstddef>

typedef __attribute__((ext_vector_type(8))) short  short8;
typedef __attribute__((ext_vector_type(4))) short  short4v;
typedef __attribute__((ext_vector_type(4))) float  f32x4;

#define BZ   16
#define LQ   2048
#define LK   2048
#define DD   64
#define QBLK 64
#define KVB  128            // kv staged per super-iter (two 64-halves)
#define NIT  (LK / KVB)     // 16

__device__ inline short f2bf(float f) {
    union { float f; uint32_t u; } x; x.f = f;
    uint32_t r = x.u + 0x7fffu + ((x.u >> 16) & 1u);   // RNE
    return (short)(r >> 16);
}

__global__ __launch_bounds__(512, 4)
void attn_fwd(const float* __restrict__ Qg, const float* __restrict__ Kg,
              const float* __restrict__ Vg, const int* __restrict__ Mg,
              float* __restrict__ Og)
{
    __shared__ short Klds[KVB * DD];      // [kv][d] bf16, row=128B, XOR-swizzled
    __shared__ short Vtlds[DD * KVB];     // [d][kv] bf16, row=256B, XOR-swizzled
    __shared__ short Plds[8][16 * 64];    // per-wave P, row=128B, XOR-swizzled
    __shared__ short Qlds[QBLK * DD];     // [q][d] bf16, row=128B, XOR-swizzled

    const int t = threadIdx.x;
    const int w = t >> 6;          // wave 0..7
    const int l = t & 63;
    const int g = l >> 4;          // quarter 0..3
    const int n = l & 15;

    // XCD-aware mapping: xcd -> batches {xcd, xcd+8}; K/V stays in per-XCD L2/L3
    const int nb   = blockIdx.x;
    const int xcd  = nb & 7;
    const int jj   = nb >> 3;              // 0..63
    const int b    = xcd + 8 * (jj >> 5);
    const int qtl  = jj & 31;
    const int qbase = qtl * QBLK;

    const int stripe = w & 3;      // q-stripe (16 rows)
    const int half   = w >> 2;     // kv half within the 128 staged

    const float* Qb = Qg + ((size_t)b * LQ + qbase) * DD;
    const float* Kb = Kg + (size_t)b * LK * DD;
    const float* Vb = Vg + (size_t)b * LK * DD;
    const int*   Mb = Mg + ((size_t)b * LQ + qbase) * (size_t)LK;

    const int sr = t >> 4;         // 0..31 (staging row group)
    const int sc = (t & 15) * 4;   // staging d0

    // ---- stage Q (f32 -> bf16, swizzled) ----
    #pragma unroll
    for (int i = 0; i < 2; ++i) {
        int q = sr + i * 32;
        f32x4 qv = *(const f32x4*)(Qb + (size_t)q * DD + sc);
        short4v qp;
        qp.x = f2bf(qv.x); qp.y = f2bf(qv.y); qp.z = f2bf(qv.z); qp.w = f2bf(qv.w);
        *(short4v*)((char*)Qlds + q * 128 + ((sc * 2) ^ ((q & 7) << 4))) = qp;
    }
    __syncthreads();

    // ---- Q A-fragments (rows stripe*16+n, K=64 -> 2 k-steps) ----
    short8 aQ[2];
    {
        int qr = stripe * 16 + n;
        #pragma unroll
        for (int s = 0; s < 2; ++s)
            aQ[s] = *(short8*)((char*)Qlds + qr * 128 + ((s * 64 + g * 16) ^ ((qr & 7) << 4)));
    }

    f32x4 Oacc[4];
    #pragma unroll
    for (int c = 0; c < 4; ++c) { Oacc[c].x = 0.f; Oacc[c].y = 0.f; Oacc[c].z = 0.f; Oacc[c].w = 0.f; }
    float m2[4]   = { -1e30f, -1e30f, -1e30f, -1e30f };
    float lsum[4] = { 0.f, 0.f, 0.f, 0.f };

    const float SC2 = 0.125f * 1.4426950408889634f;   // 1/sqrt(64) * log2(e)

    for (int it = 0; it < NIT; ++it) {
        const int kvbase = it * KVB;

        // ---- issue global loads early (K/V tiles f32, then mask dwords) ----
        f32x4 kr[4], vr[4];
        #pragma unroll
        for (int i = 0; i < 4; ++i) {
            int kv = sr + i * 32;
            kr[i] = *(const f32x4*)(Kb + (size_t)(kvbase + kv) * DD + sc);
            vr[i] = *(const f32x4*)(Vb + (size_t)(kvbase + kv) * DD + sc);
        }
        int mv[16];
        #pragma unroll
        for (int r = 0; r < 4; ++r)
            #pragma unroll
            for (int c = 0; c < 4; ++c)
                mv[r * 4 + c] = Mb[(size_t)(stripe * 16 + g * 4 + r) * LK
                                   + kvbase + half * 64 + c * 16 + n];

        __syncthreads();   // prior compute finished reading K/V LDS

        // ---- K -> LDS [kv][d] swizzled; V -> LDS transposed [d][kv] swizzled ----
        #pragma unroll
        for (int i = 0; i < 4; ++i) {
            int kv = sr + i * 32;
            short4v kp;
            kp.x = f2bf(kr[i].x); kp.y = f2bf(kr[i].y); kp.z = f2bf(kr[i].z); kp.w = f2bf(kr[i].w);
            *(short4v*)((char*)Klds + kv * 128 + ((sc * 2) ^ ((kv & 7) << 4))) = kp;
            #pragma unroll
            for (int e = 0; e < 4; ++e) {
                int d = sc + e;
                float fv = (e == 0) ? vr[i].x : (e == 1) ? vr[i].y : (e == 2) ? vr[i].z : vr[i].w;
                *((short*)((char*)Vtlds + d * 256 + ((kv * 2) ^ ((d & 7) << 4)))) = f2bf(fv);
            }
        }
        __syncthreads();   // staging complete

        // ---- QK^T: S[16q][64kv-half], 4 col-tiles x 2 k-steps ----
        f32x4 S[4];
        #pragma unroll
        for (int c = 0; c < 4; ++c) { S[c].x = 0.f; S[c].y = 0.f; S[c].z = 0.f; S[c].w = 0.f; }
        #pragma unroll
        for (int c = 0; c < 4; ++c) {
            int kvl = half * 64 + c * 16 + n;
            #pragma unroll
            for (int s = 0; s < 2; ++s) {
                short8 bK = *(short8*)((char*)Klds + kvl * 128
                                       + ((s * 64 + g * 16) ^ ((kvl & 7) << 4)));
                S[c] = __builtin_amdgcn_mfma_f32_16x16x32_bf16(aQ[s], bK, S[c], 0, 0, 0);
            }
        }

        // ---- mask + scale (exp2 domain); exact -1e9 select like reference ----
        float sv[4][4];
        #pragma unroll
        for (int r = 0; r < 4; ++r)
            #pragma unroll
            for (int c = 0; c < 4; ++c) {
                float x = S[c][r] * SC2;
                sv[r][c] = mv[r * 4 + c] ? -1.0e9f : x;
            }

        // ---- online softmax (wave-parallel, 16-lane row groups) ----
        #pragma unroll
        for (int r = 0; r < 4; ++r) {
            float mx = fmaxf(fmaxf(sv[r][0], sv[r][1]), fmaxf(sv[r][2], sv[r][3]));
            mx = fmaxf(mx, __shfl_xor(mx, 1));
            mx = fmaxf(mx, __shfl_xor(mx, 2));
            mx = fmaxf(mx, __shfl_xor(mx, 4));
            mx = fmaxf(mx, __shfl_xor(mx, 8));
            float mnew = fmaxf(m2[r], mx);
            float resc = exp2f(m2[r] - mnew);
            m2[r] = mnew;
            lsum[r] *= resc;
            #pragma unroll
            for (int c = 0; c < 4; ++c) Oacc[c][r] *= resc;

            float rs = 0.f;
            int q = g * 4 + r;
            #pragma unroll
            for (int c = 0; c < 4; ++c) {
                float p = exp2f(sv[r][c] - mnew);
                rs += p;
                *((short*)((char*)Plds[w] + q * 128
                           + (((c * 16 + n) * 2) ^ ((q & 7) << 4)))) = f2bf(p);
            }
            rs += __shfl_xor(rs, 1);
            rs += __shfl_xor(rs, 2);
            rs += __shfl_xor(rs, 4);
            rs += __shfl_xor(rs, 8);
            lsum[r] += rs;
        }

        // ---- PV: Oacc += P[16][64] * V[64][64-d]  (P per-wave, no barrier) ----
        #pragma unroll
        for (int s = 0; s < 2; ++s) {
            short8 aP = *(short8*)((char*)Plds[w] + n * 128
                                   + ((s * 64 + g * 16) ^ ((n & 7) << 4)));
            #pragma unroll
            for (int c = 0; c < 4; ++c) {
                int d = c * 16 + n;
                short8 bV = *(short8*)((char*)Vtlds + d * 256
                                       + ((half * 128 + s * 64 + g * 16) ^ ((d & 7) << 4)));
                Oacc[c] = __builtin_amdgcn_mfma_f32_16x16x32_bf16(aP, bV, Oacc[c], 0, 0, 0);
            }
        }
    }

    // ---- merge kv-halves (wave pairs w, w^4) and store ----
    __syncthreads();
    float* mrg = (float*)Klds;     // 4 stripes x 16x64 f32 = 16 KB
    float* mlb = (float*)Vtlds;    // 64 rows x {m,l}

    if (half == 1) {
        #pragma unroll
        for (int r = 0; r < 4; ++r) {
            int qloc = g * 4 + r;
            int q = stripe * 16 + qloc;
            if (n == 0) { mlb[q * 2] = m2[r]; mlb[q * 2 + 1] = lsum[r]; }
            #pragma unroll
            for (int c = 0; c < 4; ++c)
                mrg[stripe * 1024 + qloc * 64 + c * 16 + n] = Oacc[c][r];
        }
    }
    __syncthreads();
    if (half == 0) {
        #pragma unroll
        for (int r = 0; r < 4; ++r) {
            int qloc = g * 4 + r;
            int q = stripe * 16 + qloc;
            float mB = mlb[q * 2], lB = mlb[q * 2 + 1];
            float ms = fmaxf(m2[r], mB);
            float sA = exp2f(m2[r] - ms);
            float sB = exp2f(mB - ms);
            float inv = 1.0f / (lsum[r] * sA + lB * sB);
            #pragma unroll
            for (int c = 0; c < 4; ++c) {
                float oB = mrg[stripe * 1024 + qloc * 64 + c * 16 + n];
                Og[((size_t)b * LQ + qbase + q) * DD + c * 16 + n] =
                    (Oacc[c][r] * sA + oB * sB) * inv;
            }
        }
    }
}

extern "C" void kernel_launch(void* const* d_in, const int* in_sizes, int n_in,
                              void* d_out, int out_size, void* d_ws, size_t ws_size,
                              hipStream_t stream) {
    const float* q = (const float*)d_in[0];
    const float* k = (const float*)d_in[1];
    const float* v = (const float*)d_in[2];
    const int*   m = (const int*)d_in[3];
    float* out = (float*)d_out;
    dim3 grid(BZ * (LQ / QBLK) * 1);   // 16 batches * 32 qtiles = 512
    dim3 block(512);
    attn_fwd<<<grid, block, 0, stream>>>(q, k, v, m, out);
}